// Round 9
// baseline (297.110 us; speedup 1.0000x reference)
//
#include <hip/hip_runtime.h>

#define N_SEG 256
#define HIDDEN 512
#define CHUNKS 16
#define NB (N_SEG * CHUNKS)   // 4096 blocks
#define NEG_INF (-__builtin_inff())

// One tiny block: seg_off[0..256] via guarded windowed binary search (window
// +-2048 around arithmetic expectation; falls back to full range if the guard
// probes fail, so it is correct for ANY sorted input), and zero the 256
// per-segment completion counters used by the in-fused merge.
__global__ __launch_bounds__(512) void setup_kernel(
    const int* __restrict__ batch, int* __restrict__ seg_off,
    int* __restrict__ cnt, int n) {
    int t = threadIdx.x;
    if (t >= 256) cnt[t - 256] = 0;
    if (t <= 256) {
        int es = (int)(((long long)n * t) >> 8);
        int wlo = es - 2048; if (wlo < 0) wlo = 0;
        int whi = es + 2048; if (whi > n) whi = n;
        bool ok = (wlo == 0 || batch[wlo - 1] < t) && (whi == n || batch[whi] >= t);
        int lo = ok ? wlo : 0;
        int hi = ok ? whi : n;
        while (lo < hi) { int mid = (lo + hi) >> 1; if (batch[mid] < t) lo = mid + 1; else hi = mid; }
        seg_off[t] = lo;
    }
}

// One block per (segment, chunk): seg bounds from seg_off (2 broadcast loads),
// c-th 1/16 slice, 4 waves interleaved (one sequential ~8KB-burst stream),
// online softmax + depth-1 prefetch, LDS merge of the 4 waves, partial
// (m,d,acc[512]) at slot = blockIdx.x. Then release-fence + atomicAdd on the
// segment counter; the 16th arrival softmax-merges all 16 partials (agent-scope
// loads for cross-XCD visibility) and writes out[s] directly. No merge kernel.
__global__ __launch_bounds__(256) void fused_kernel(
    const float* __restrict__ x, const float* __restrict__ W,
    const int* __restrict__ seg_off,
    float* __restrict__ pacc, float* __restrict__ pm, float* __restrict__ pd,
    int* __restrict__ cnt, float* __restrict__ out) {
    int b = blockIdx.x;
    int s = b >> 4, c = b & 15;
    int t = threadIdx.x, lane = t & 63, w = t >> 6;

    int ss = seg_off[s], se = seg_off[s + 1];
    int len = se - ss;
    int st = ss + (int)(((long long)len * c) >> 4);
    int en = ss + (int)(((long long)len * (c + 1)) >> 4);

    __shared__ float sm[4], sd[4];
    __shared__ float sacc[4][HIDDEN];  // 8 KB
    __shared__ int slast;

    if (st < en) {
        float4 w0 = *(const float4*)(W + lane * 8);
        float4 w1 = *(const float4*)(W + lane * 8 + 4);
        float m = NEG_INF, d = 0.0f;
        float acc[8] = {0, 0, 0, 0, 0, 0, 0, 0};

        int i = st + w;
        bool have = i < en;   // wave-uniform
        float4 a0, a1;
        if (have) {
            const float* xr = x + (size_t)i * HIDDEN + lane * 8;
            a0 = *(const float4*)xr; a1 = *(const float4*)(xr + 4);
        }
        while (have) {
            int inext = i + 4;
            bool hnext = inext < en;
            float4 b0, b1;
            if (hnext) {  // depth-1 prefetch of next owned row
                const float* xr = x + (size_t)inext * HIDDEN + lane * 8;
                b0 = *(const float4*)xr; b1 = *(const float4*)(xr + 4);
            }
            float g = a0.x * w0.x + a0.y * w0.y + a0.z * w0.z + a0.w * w0.w
                    + a1.x * w1.x + a1.y * w1.y + a1.z * w1.z + a1.w * w1.w;
            #pragma unroll
            for (int off = 32; off; off >>= 1) g += __shfl_xor(g, off, 64);
            float mn = fmaxf(m, g);
            float scale = __expf(m - mn);  // 0 on first row (m=-inf)
            float p = __expf(g - mn);
            d = d * scale + p;
            acc[0] = acc[0] * scale + p * a0.x;  acc[1] = acc[1] * scale + p * a0.y;
            acc[2] = acc[2] * scale + p * a0.z;  acc[3] = acc[3] * scale + p * a0.w;
            acc[4] = acc[4] * scale + p * a1.x;  acc[5] = acc[5] * scale + p * a1.y;
            acc[6] = acc[6] * scale + p * a1.z;  acc[7] = acc[7] * scale + p * a1.w;
            m = mn;
            a0 = b0; a1 = b1; i = inext; have = hnext;
        }

        // block-level softmax merge of the 4 waves via LDS
        if (lane == 0) sm[w] = m;
        __syncthreads();
        float M = fmaxf(fmaxf(sm[0], sm[1]), fmaxf(sm[2], sm[3]));  // wave 0 nonempty
        float scale = (m == NEG_INF) ? 0.0f : __expf(m - M);        // short-slice waves
        if (lane == 0) sd[w] = d * scale;
        #pragma unroll
        for (int j = 0; j < 8; ++j) sacc[w][lane * 8 + j] = acc[j] * scale;
        __syncthreads();
        if (t == 0) { pm[b] = M; pd[b] = sd[0] + sd[1] + sd[2] + sd[3]; }
        for (int j = t; j < HIDDEN; j += 256)
            pacc[(size_t)b * HIDDEN + j] = sacc[0][j] + sacc[1][j] + sacc[2][j] + sacc[3][j];
    } else {  // empty chunk: neutral partial (still participates in counting)
        if (t == 0) { pm[b] = NEG_INF; pd[b] = 0.0f; }
        for (int j = t; j < HIDDEN; j += 256) pacc[(size_t)b * HIDDEN + j] = 0.0f;
    }

    // ---- completion counting: 16th arrival merges the segment ----
    __syncthreads();                    // drain this block's partial writes
    if (t == 0) {
        __threadfence();                // release: make partial visible device-wide
        int old = atomicAdd(&cnt[s], 1);
        slast = (old == CHUNKS - 1);
    }
    __syncthreads();
    if (!slast) return;

    __threadfence();                    // acquire side
    int k0 = s * CHUNKS;
    float M = NEG_INF;
    #pragma unroll
    for (int k = 0; k < CHUNKS; ++k)
        M = fmaxf(M, __hip_atomic_load(&pm[k0 + k], __ATOMIC_RELAXED, __HIP_MEMORY_SCOPE_AGENT));
    float D = 0.0f;
    #pragma unroll
    for (int k = 0; k < CHUNKS; ++k) {
        float mk = __hip_atomic_load(&pm[k0 + k], __ATOMIC_RELAXED, __HIP_MEMORY_SCOPE_AGENT);
        float wk = (mk == NEG_INF) ? 0.0f : __expf(mk - M);
        D += __hip_atomic_load(&pd[k0 + k], __ATOMIC_RELAXED, __HIP_MEMORY_SCOPE_AGENT) * wk;
    }
    float invD = 1.0f / (D + 1e-16f);
    float n0 = 0.0f, n1 = 0.0f;
    #pragma unroll
    for (int k = 0; k < CHUNKS; ++k) {
        float mk = __hip_atomic_load(&pm[k0 + k], __ATOMIC_RELAXED, __HIP_MEMORY_SCOPE_AGENT);
        if (mk == NEG_INF) continue;    // empty chunk contributes nothing
        float wk = __expf(mk - M);
        n0 += __hip_atomic_load(&pacc[(size_t)(k0 + k) * HIDDEN + t],
                                __ATOMIC_RELAXED, __HIP_MEMORY_SCOPE_AGENT) * wk;
        n1 += __hip_atomic_load(&pacc[(size_t)(k0 + k) * HIDDEN + 256 + t],
                                __ATOMIC_RELAXED, __HIP_MEMORY_SCOPE_AGENT) * wk;
    }
    out[s * HIDDEN + t] = n0 * invD;         // empty segment -> 0
    out[s * HIDDEN + 256 + t] = n1 * invD;
}

extern "C" void kernel_launch(void* const* d_in, const int* in_sizes, int n_in,
                              void* d_out, int out_size, void* d_ws, size_t ws_size,
                              hipStream_t stream) {
    const float* x     = (const float*)d_in[0];
    const int*   batch = (const int*)d_in[1];
    const float* W     = (const float*)d_in[2];
    int n = in_sizes[1];
    float* out = (float*)d_out;

    // ws: pacc[NB*512] (16B-aligned first) | pm[NB] | pd[NB] | cnt[256] | seg_off[257]
    float* pacc = (float*)d_ws;
    float* pm   = pacc + (size_t)NB * HIDDEN;
    float* pd   = pm + NB;
    int* cnt     = (int*)(pd + NB);
    int* seg_off = cnt + N_SEG;

    setup_kernel<<<1, 512, 0, stream>>>(batch, seg_off, cnt, n);
    fused_kernel<<<NB, 256, 0, stream>>>(x, W, seg_off, pacc, pm, pd, cnt, out);
}

// Round 10
// 45.251 us; speedup vs baseline: 6.5658x; 6.5658x over previous
//
#include <hip/hip_runtime.h>

#define N_SEG 256
#define HIDDEN 512
#define CHUNKS 16
#define NB (N_SEG * CHUNKS)   // 4096 blocks
#define NEG_INF (-__builtin_inff())

// Boundary scatter: one flat parallel pass over sorted batch, no dependent
// load chains. seg_off[s] = lower_bound(batch, s) for s in [0,256].
// Total scatter-loop iterations across all threads <= N_SEG.
__global__ __launch_bounds__(256) void seg_kernel(
    const int* __restrict__ batch, int* __restrict__ seg_off, int n) {
    int i = blockIdx.x * blockDim.x + threadIdx.x;
    if (i >= n) return;
    int b0 = batch[i];
    if (i == 0)
        for (int s = 0; s <= b0; ++s) seg_off[s] = 0;
    if (i == n - 1) {
        for (int s = b0 + 1; s <= N_SEG; ++s) seg_off[s] = n;
    } else {
        int b1 = batch[i + 1];
        for (int s = b0 + 1; s <= b1; ++s) seg_off[s] = i + 1;
    }
}

// One block per (segment, chunk): bounds from seg_off (2 scalar loads), c-th
// 1/16 slice, 4 waves interleaved (one sequential ~8KB-burst stream), online
// softmax + depth-1 prefetch, LDS merge of the 4 waves, one partial
// (m, d, acc[512]) at slot = blockIdx.x.  (r7 body, searches removed.)
__global__ __launch_bounds__(256) void fused_kernel(
    const float* __restrict__ x, const float* __restrict__ W,
    const int* __restrict__ seg_off,
    float* __restrict__ pacc, float* __restrict__ pm, float* __restrict__ pd) {
    int b = blockIdx.x;
    int s = b >> 4, c = b & 15;
    int t = threadIdx.x, lane = t & 63, w = t >> 6;

    int ss = seg_off[s], se = seg_off[s + 1];
    int len = se - ss;
    int st = ss + (int)(((long long)len * c) >> 4);
    int en = ss + (int)(((long long)len * (c + 1)) >> 4);

    if (st >= en) {  // empty chunk: neutral partial
        if (t == 0) { pm[b] = NEG_INF; pd[b] = 0.0f; }
        for (int j = t; j < HIDDEN; j += 256) pacc[(size_t)b * HIDDEN + j] = 0.0f;
        return;
    }

    float4 w0 = *(const float4*)(W + lane * 8);
    float4 w1 = *(const float4*)(W + lane * 8 + 4);
    float m = NEG_INF, d = 0.0f;
    float acc[8] = {0, 0, 0, 0, 0, 0, 0, 0};

    int i = st + w;
    bool have = i < en;   // wave-uniform
    float4 a0, a1;
    if (have) {
        const float* xr = x + (size_t)i * HIDDEN + lane * 8;
        a0 = *(const float4*)xr; a1 = *(const float4*)(xr + 4);
    }
    while (have) {
        int inext = i + 4;
        bool hnext = inext < en;
        float4 b0, b1;
        if (hnext) {  // depth-1 prefetch of next owned row
            const float* xr = x + (size_t)inext * HIDDEN + lane * 8;
            b0 = *(const float4*)xr; b1 = *(const float4*)(xr + 4);
        }
        float g = a0.x * w0.x + a0.y * w0.y + a0.z * w0.z + a0.w * w0.w
                + a1.x * w1.x + a1.y * w1.y + a1.z * w1.z + a1.w * w1.w;
        #pragma unroll
        for (int off = 32; off; off >>= 1) g += __shfl_xor(g, off, 64);
        float mn = fmaxf(m, g);
        float scale = __expf(m - mn);  // 0 on first row (m=-inf), 1 if max unchanged
        float p = __expf(g - mn);
        d = d * scale + p;
        acc[0] = acc[0] * scale + p * a0.x;  acc[1] = acc[1] * scale + p * a0.y;
        acc[2] = acc[2] * scale + p * a0.z;  acc[3] = acc[3] * scale + p * a0.w;
        acc[4] = acc[4] * scale + p * a1.x;  acc[5] = acc[5] * scale + p * a1.y;
        acc[6] = acc[6] * scale + p * a1.z;  acc[7] = acc[7] * scale + p * a1.w;
        m = mn;
        a0 = b0; a1 = b1; i = inext; have = hnext;
    }

    // block-level softmax merge of the 4 waves via LDS
    __shared__ float sm[4], sd[4];
    __shared__ float sacc[4][HIDDEN];  // 8 KB
    if (lane == 0) sm[w] = m;
    __syncthreads();
    float M = fmaxf(fmaxf(sm[0], sm[1]), fmaxf(sm[2], sm[3]));  // wave 0 nonempty -> finite
    float scale = (m == NEG_INF) ? 0.0f : __expf(m - M);
    if (lane == 0) sd[w] = d * scale;
    #pragma unroll
    for (int j = 0; j < 8; ++j) sacc[w][lane * 8 + j] = acc[j] * scale;
    __syncthreads();
    if (t == 0) { pm[b] = M; pd[b] = sd[0] + sd[1] + sd[2] + sd[3]; }
    for (int j = t; j < HIDDEN; j += 256)
        pacc[(size_t)b * HIDDEN + j] = sacc[0][j] + sacc[1][j] + sacc[2][j] + sacc[3][j];
}

// One block per segment: softmax-merge its 16 fixed slots [16s, 16s+16), write out.
__global__ __launch_bounds__(256) void merge_kernel(
    const float* __restrict__ pacc, const float* __restrict__ pm,
    const float* __restrict__ pd, float* __restrict__ out) {
    int s = blockIdx.x, t = threadIdx.x;
    int k0 = s * CHUNKS;
    float M = NEG_INF;
    #pragma unroll
    for (int k = 0; k < CHUNKS; ++k) M = fmaxf(M, pm[k0 + k]);
    float wts[CHUNKS];
    float D = 0.0f;
    #pragma unroll
    for (int k = 0; k < CHUNKS; ++k) {
        float mk = pm[k0 + k];
        float wk = (mk == NEG_INF) ? 0.0f : __expf(mk - M);  // also guards empty segment
        wts[k] = wk;
        D += pd[k0 + k] * wk;
    }
    float invD = 1.0f / (D + 1e-16f);
    #pragma unroll
    for (int rep = 0; rep < 2; ++rep) {
        int col = t + rep * 256;
        float num = 0.0f;
        #pragma unroll
        for (int k = 0; k < CHUNKS; ++k)
            num += pacc[(size_t)(k0 + k) * HIDDEN + col] * wts[k];
        out[s * HIDDEN + col] = num * invD;  // empty segment -> 0
    }
}

extern "C" void kernel_launch(void* const* d_in, const int* in_sizes, int n_in,
                              void* d_out, int out_size, void* d_ws, size_t ws_size,
                              hipStream_t stream) {
    const float* x     = (const float*)d_in[0];
    const int*   batch = (const int*)d_in[1];
    const float* W     = (const float*)d_in[2];
    int n = in_sizes[1];
    float* out = (float*)d_out;

    // ws: pacc[NB*512] (16B-aligned first) | pm[NB] | pd[NB] | seg_off[257]
    float* pacc = (float*)d_ws;
    float* pm   = pacc + (size_t)NB * HIDDEN;
    float* pd   = pm + NB;
    int* seg_off = (int*)(pd + NB);

    seg_kernel<<<(n + 255) / 256, 256, 0, stream>>>(batch, seg_off, n);
    fused_kernel<<<NB, 256, 0, stream>>>(x, W, seg_off, pacc, pm, pd);
    merge_kernel<<<N_SEG, 256, 0, stream>>>(pacc, pm, pd, out);
}

// Round 11
// 45.232 us; speedup vs baseline: 6.5685x; 1.0004x over previous
//
#include <hip/hip_runtime.h>

#define N_SEG 256
#define HIDDEN 512
#define CHUNKS 16
#define NB (N_SEG * CHUNKS)   // 4096 blocks
#define NEG_INF (-__builtin_inff())

// Boundary scatter: one flat parallel pass over sorted batch, no dependent
// load chains. seg_off[s] = lower_bound(batch, s) for s in [0,256].
// Total scatter-loop iterations across all threads <= N_SEG.
__global__ __launch_bounds__(256) void seg_kernel(
    const int* __restrict__ batch, int* __restrict__ seg_off, int n) {
    int i = blockIdx.x * blockDim.x + threadIdx.x;
    if (i >= n) return;
    int b0 = batch[i];
    if (i == 0)
        for (int s = 0; s <= b0; ++s) seg_off[s] = 0;
    if (i == n - 1) {
        for (int s = b0 + 1; s <= N_SEG; ++s) seg_off[s] = n;
    } else {
        int b1 = batch[i + 1];
        for (int s = b0 + 1; s <= b1; ++s) seg_off[s] = i + 1;
    }
}

// One block per (segment, chunk): bounds from seg_off (2 scalar loads; W vector
// loads issued first to cover that bubble), c-th 1/16 slice, 4 waves
// interleaved (one sequential ~8KB-burst stream), online softmax + depth-1
// prefetch, LDS merge of the 4 waves, one partial (m,d,acc[512]) at slot b.
__global__ __launch_bounds__(256) void fused_kernel(
    const float* __restrict__ x, const float* __restrict__ W,
    const int* __restrict__ seg_off,
    float* __restrict__ pacc, float* __restrict__ pm, float* __restrict__ pd) {
    int b = blockIdx.x;
    int s = b >> 4, c = b & 15;
    int t = threadIdx.x, lane = t & 63, w = t >> 6;

    // issue W loads before the dependent seg_off scalar loads
    float4 w0 = *(const float4*)(W + lane * 8);
    float4 w1 = *(const float4*)(W + lane * 8 + 4);

    int ss = seg_off[s], se = seg_off[s + 1];
    int len = se - ss;
    int st = ss + (int)(((long long)len * c) >> 4);
    int en = ss + (int)(((long long)len * (c + 1)) >> 4);

    if (st >= en) {  // empty chunk: neutral partial
        if (t == 0) { pm[b] = NEG_INF; pd[b] = 0.0f; }
        for (int j = t; j < HIDDEN; j += 256) pacc[(size_t)b * HIDDEN + j] = 0.0f;
        return;
    }

    float m = NEG_INF, d = 0.0f;
    float acc[8] = {0, 0, 0, 0, 0, 0, 0, 0};

    int i = st + w;
    bool have = i < en;   // wave-uniform
    float4 a0, a1;
    if (have) {
        const float* xr = x + (size_t)i * HIDDEN + lane * 8;
        a0 = *(const float4*)xr; a1 = *(const float4*)(xr + 4);
    }
    while (have) {
        int inext = i + 4;
        bool hnext = inext < en;
        float4 b0, b1;
        if (hnext) {  // depth-1 prefetch of next owned row
            const float* xr = x + (size_t)inext * HIDDEN + lane * 8;
            b0 = *(const float4*)xr; b1 = *(const float4*)(xr + 4);
        }
        float g = a0.x * w0.x + a0.y * w0.y + a0.z * w0.z + a0.w * w0.w
                + a1.x * w1.x + a1.y * w1.y + a1.z * w1.z + a1.w * w1.w;
        #pragma unroll
        for (int off = 32; off; off >>= 1) g += __shfl_xor(g, off, 64);
        float mn = fmaxf(m, g);
        float scale = __expf(m - mn);  // 0 on first row (m=-inf), 1 if max unchanged
        float p = __expf(g - mn);
        d = d * scale + p;
        acc[0] = acc[0] * scale + p * a0.x;  acc[1] = acc[1] * scale + p * a0.y;
        acc[2] = acc[2] * scale + p * a0.z;  acc[3] = acc[3] * scale + p * a0.w;
        acc[4] = acc[4] * scale + p * a1.x;  acc[5] = acc[5] * scale + p * a1.y;
        acc[6] = acc[6] * scale + p * a1.z;  acc[7] = acc[7] * scale + p * a1.w;
        m = mn;
        a0 = b0; a1 = b1; i = inext; have = hnext;
    }

    // block-level softmax merge of the 4 waves via LDS
    __shared__ float sm[4], sd[4];
    __shared__ float sacc[4][HIDDEN];  // 8 KB
    if (lane == 0) sm[w] = m;
    __syncthreads();
    float M = fmaxf(fmaxf(sm[0], sm[1]), fmaxf(sm[2], sm[3]));  // wave 0 nonempty -> finite
    float scale = (m == NEG_INF) ? 0.0f : __expf(m - M);
    if (lane == 0) sd[w] = d * scale;
    #pragma unroll
    for (int j = 0; j < 8; ++j) sacc[w][lane * 8 + j] = acc[j] * scale;
    __syncthreads();
    if (t == 0) { pm[b] = M; pd[b] = sd[0] + sd[1] + sd[2] + sd[3]; }
    for (int j = t; j < HIDDEN; j += 256)
        pacc[(size_t)b * HIDDEN + j] = sacc[0][j] + sacc[1][j] + sacc[2][j] + sacc[3][j];
}

// 4 blocks per segment (128 columns each): softmax-merge the segment's 16
// fixed slots. 1024 blocks / 128 threads -> 4x the latency-hiding of the old
// 256-block version; per thread: 16 independent pacc loads, one wait.
__global__ __launch_bounds__(128) void merge_kernel(
    const float* __restrict__ pacc, const float* __restrict__ pm,
    const float* __restrict__ pd, float* __restrict__ out) {
    int s = blockIdx.x >> 2;
    int col = ((blockIdx.x & 3) << 7) + threadIdx.x;
    int k0 = s * CHUNKS;
    float M = NEG_INF;
    #pragma unroll
    for (int k = 0; k < CHUNKS; ++k) M = fmaxf(M, pm[k0 + k]);
    float wts[CHUNKS];
    float D = 0.0f;
    #pragma unroll
    for (int k = 0; k < CHUNKS; ++k) {
        float mk = pm[k0 + k];
        float wk = (mk == NEG_INF) ? 0.0f : __expf(mk - M);  // also guards empty segment
        wts[k] = wk;
        D += pd[k0 + k] * wk;
    }
    float invD = 1.0f / (D + 1e-16f);
    float num = 0.0f;
    #pragma unroll
    for (int k = 0; k < CHUNKS; ++k)
        num += pacc[(size_t)(k0 + k) * HIDDEN + col] * wts[k];
    out[s * HIDDEN + col] = num * invD;  // empty segment -> 0
}

extern "C" void kernel_launch(void* const* d_in, const int* in_sizes, int n_in,
                              void* d_out, int out_size, void* d_ws, size_t ws_size,
                              hipStream_t stream) {
    const float* x     = (const float*)d_in[0];
    const int*   batch = (const int*)d_in[1];
    const float* W     = (const float*)d_in[2];
    int n = in_sizes[1];
    float* out = (float*)d_out;

    // ws: pacc[NB*512] (16B-aligned first) | pm[NB] | pd[NB] | seg_off[257]
    float* pacc = (float*)d_ws;
    float* pm   = pacc + (size_t)NB * HIDDEN;
    float* pd   = pm + NB;
    int* seg_off = (int*)(pd + NB);

    seg_kernel<<<(n + 255) / 256, 256, 0, stream>>>(batch, seg_off, n);
    fused_kernel<<<NB, 256, 0, stream>>>(x, W, seg_off, pacc, pm, pd);
    merge_kernel<<<N_SEG * 4, 128, 0, stream>>>(pacc, pm, pd, out);
}